// Round 11
// baseline (577.162 us; speedup 1.0000x reference)
//
#include <hip/hip_runtime.h>

typedef unsigned short u16;
typedef unsigned int   u32;

typedef __attribute__((ext_vector_type(8))) __bf16 bf16x8;
typedef __attribute__((ext_vector_type(4))) float  f32x4;

__device__ __forceinline__ u16 f2bf(float f) {
  union { float f; u32 u; } v; v.f = f;
  return (u16)((v.u + 0x7fffu + ((v.u >> 16) & 1u)) >> 16);
}
__device__ __forceinline__ float bf2f(u16 h) {
  union { u32 u; float f; } v; v.u = ((u32)h) << 16;
  return v.f;
}
__device__ __forceinline__ u32 pk2(float a, float b) {
  return (u32)f2bf(a) | ((u32)f2bf(b) << 16);
}
__device__ __forceinline__ void gl2lds16(const void* g, void* l) {
  __builtin_amdgcn_global_load_lds(
      (const __attribute__((address_space(1))) u32*)g,
      (__attribute__((address_space(3))) u32*)l, 16, 0, 0);
}

// ---------- enc f32 -> encb bf16 (plain row-major) ----------
__global__ __launch_bounds__(256) void convert_kernel(
    const float* __restrict__ enc, u16* __restrict__ encb) {
  const size_t total = (size_t)131072 * 1024 / 8;
  const size_t stride = (size_t)gridDim.x * 256;
  for (size_t i = (size_t)blockIdx.x * 256 + threadIdx.x; i < total; i += stride) {
    float4 v0 = *reinterpret_cast<const float4*>(enc + i * 8);
    float4 v1 = *reinterpret_cast<const float4*>(enc + i * 8 + 4);
    uint4 o;
    o.x = pk2(v0.x, v0.y); o.y = pk2(v0.z, v0.w);
    o.z = pk2(v1.x, v1.y); o.w = pk2(v1.z, v1.w);
    *reinterpret_cast<uint4*>(encb + i * 8) = o;
  }
}

// ---------- W1 [K=1024][N=1024] f32 -> W1s pre-swizzled bf16 ----------
__global__ __launch_bounds__(256) void transpose_w1_kernel(
    const float* __restrict__ W1, u16* __restrict__ W1s) {
  __shared__ float tile[64][65];
  const int k0 = blockIdx.x * 64, n0 = blockIdx.y * 64;
  const int tx = threadIdx.x & 63, ty = threadIdx.x >> 6;
#pragma unroll
  for (int i = 0; i < 16; ++i) {
    int r = ty + i * 4;
    tile[r][tx] = W1[(k0 + r) * 1024 + n0 + tx];
  }
  __syncthreads();
#pragma unroll
  for (int i = 0; i < 16; ++i) {
    int r = ty * 16 + i;
    int n = n0 + r;
    int k = k0 + tx;
    int kt = k >> 5, kk = k & 31;
    W1s[kt * 32768 + n * 32 + (kk ^ (((n >> 1) & 3) << 3))] = f2bf(tile[tx][r]);
  }
}

// ---------- pdp[ec][b][d] = sum_{e in chunk} dec[b][e] * W2[e][d] ----------
__global__ __launch_bounds__(256) void proj_dec_partial(
    const float* __restrict__ dec, const float* __restrict__ W2,
    float* __restrict__ pdp) {
  __shared__ float sdec[64][64];
  const int e0 = blockIdx.x * 64, d0 = blockIdx.y * 64;
  const int dl = threadIdx.x & 63, bg = threadIdx.x >> 6;
#pragma unroll
  for (int i = 0; i < 16; ++i) {
    int flat = threadIdx.x + i * 256;
    sdec[flat >> 6][flat & 63] = dec[(flat >> 6) * 1024 + e0 + (flat & 63)];
  }
  __syncthreads();
  const int d = d0 + dl;
  float acc[16];
#pragma unroll
  for (int i = 0; i < 16; ++i) acc[i] = 0.f;
  for (int e = 0; e < 64; ++e) {
    float w2 = W2[(size_t)(e0 + e) * 1024 + d];
#pragma unroll
    for (int bb = 0; bb < 16; ++bb)
      acc[bb] += sdec[bg * 16 + bb][e] * w2;
  }
#pragma unroll
  for (int bb = 0; bb < 16; ++bb)
    pdp[(size_t)blockIdx.x * 65536 + (size_t)(bg * 16 + bb) * 1024 + d] = acc[bb];
}

__global__ __launch_bounds__(256) void proj_dec_reduce(
    const float* __restrict__ pdp, const float* __restrict__ W2b,
    const float* __restrict__ W1b, float* __restrict__ pd) {
  const int i = blockIdx.x * 256 + threadIdx.x;
  const int d = i & 1023;
  float s = W2b[d] + W1b[d];
#pragma unroll
  for (int j = 0; j < 16; ++j) s += pdp[(size_t)j * 65536 + i];
  pd[i] = s;
}

// ---------- legacy proj_dec (small-ws fallback only) ----------
__global__ __launch_bounds__(256) void proj_dec_kernel(
    const float* __restrict__ dec, const float* __restrict__ W2,
    const float* __restrict__ W2b, const float* __restrict__ W1b,
    float* __restrict__ pd) {
  __shared__ float sdec[16 * 256];
  const int dl = threadIdx.x & 63;
  const int bg = threadIdx.x >> 6;
  const int d  = blockIdx.x * 64 + dl;
  const int b0 = blockIdx.y * 16;
  float acc[4];
#pragma unroll
  for (int i = 0; i < 4; ++i) acc[i] = 0.f;
  for (int et = 0; et < 4; ++et) {
    __syncthreads();
#pragma unroll
    for (int i = 0; i < 16; ++i) {
      int flat = threadIdx.x + i * 256;
      sdec[flat] = dec[(b0 + (flat >> 8)) * 1024 + et * 256 + (flat & 255)];
    }
    __syncthreads();
    for (int e = 0; e < 256; ++e) {
      float w2 = W2[(et * 256 + e) * 1024 + d];
#pragma unroll
      for (int bb = 0; bb < 4; ++bb)
        acc[bb] += sdec[(bg * 4 + bb) * 256 + e] * w2;
    }
  }
  float bias = W2b[d] + W1b[d];
#pragma unroll
  for (int bb = 0; bb < 4; ++bb)
    pd[(b0 + bg * 4 + bb) * 1024 + d] = acc[bb] + bias;
}

// ---------- 256x256-tile fused GEMM + tanh + V-dot (big-ws path) ----------
// Staging-BW analysis: 128x256 tile needs 158 B/cyc/CU of L2->LDS staging at
// full MFMA rate vs ~60-65 achievable -> 39% ceiling (R7/R9 measured). 256x256
// needs only 103 -> ~60% ceiling. 512 thr = 8 waves (2m x 4n), wave-tile
// 128x64 (acc 128 VGPR, launch_bounds(512,2)), 3-slot ring (96KB, 1 blk/CU),
// prefetch distance 2. Per K-step, 2 phases of {ds_read, stage-issue, barrier,
// setprio, 16 MFMA, setprio, barrier}; ONE vmcnt(4) per step before phase-1's
// pre-MFMA barrier (drains stage(kt+1); following barrier globalizes the
// per-wave guarantee - m201 pattern). Ring overwrite-safety: data kt-1's
// lgkm waits precede step-(kt-1)'s post-MFMA barrier, which precedes the
// stage into that slot at step kt+... Tail: dummy stages keep vmcnt uniform.
__global__ __launch_bounds__(512, 2) void score256_kernel(
    const u16* __restrict__ encb, const u16* __restrict__ W1s,
    const float* __restrict__ pd, const float* __restrict__ Vw,
    float* __restrict__ spart) {
  __shared__ __align__(16) u16 As[3][8192];  // 3 x 16 KB (256 r x 32 k)
  __shared__ __align__(16) u16 Bs[3][8192];  // 3 x 16 KB (256 c x 32 k)
  __shared__ float sc2[8][128];              // 4 KB

  const int tid  = threadIdx.x;
  const int lane = tid & 63;
  const int wid  = tid >> 6;
  const int wm = wid >> 2, wn = wid & 3;
  const int l15 = lane & 15, l4 = lane >> 4;
  const int bid = blockIdx.x;
  const int rg  = ((bid >> 5) << 3) | (bid & 7);  // 0..511; 4 ns of a rg share XCD
  const int ns  = (bid >> 3) & 3;
  const long row0 = (long)rg * 256;
  const int b = rg >> 3;  // 8 row-groups per batch

  // A staging: thread t copies granules t and t+512 of the 16KB slot; source
  // granule index carries the swizzle (LDS dest linear; rule both-sides).
  const int r0 = tid >> 2, j0 = tid & 3;
  const int r1 = r0 + 128;
  const u16* asrc0 = encb + (size_t)(row0 + r0) * 1024 + ((j0 ^ ((r0 >> 1) & 3)) << 3);
  const u16* asrc1 = encb + (size_t)(row0 + r1) * 1024 + ((j0 ^ ((r1 >> 1) & 3)) << 3);
  // B staging: linear copy of the pre-swizzled 16KB chunk.
  const u16* bsrc = W1s + ns * 8192 + tid * 8;

#define STAGE_A(s, k) do { \
    gl2lds16(asrc0 + (k) * 32, &As[s][tid * 8]); \
    gl2lds16(asrc1 + (k) * 32, &As[s][tid * 8 + 4096]); } while (0)
#define STAGE_B(s, k) do { \
    gl2lds16(bsrc + (size_t)(k) * 32768, &Bs[s][tid * 8]); \
    gl2lds16(bsrc + (size_t)(k) * 32768 + 4096, &Bs[s][tid * 8 + 4096]); } while (0)

  f32x4 acc[8][4];
#pragma unroll
  for (int m = 0; m < 8; ++m)
#pragma unroll
    for (int n = 0; n < 4; ++n) acc[m][n] = (f32x4){0, 0, 0, 0};

  const int kA   = (l4 * 8) ^ (((l15 >> 1) & 3) << 3);
  const int arow = wm * 128 + l15;   // phase0 rows arow+mf*16; phase1 +64
  const int brow = wn * 64 + l15;

  // prologue: stage slots 0,1 (8 loads); drain slot 0 (vmcnt(4)); globalize.
  STAGE_A(0, 0); STAGE_B(0, 0);
  STAGE_A(1, 1); STAGE_B(1, 1);
  asm volatile("s_waitcnt vmcnt(4)" ::: "memory");
  __builtin_amdgcn_s_barrier();

  int slot = 0, ps = 2;
  for (int kt = 0; kt < 32; ++kt) {
    const int pk = (kt + 2) & 31;  // tail wraps -> dummy stage into dead slot
    bf16x8 af[4], bf[4];
    // ---- phase 0: m0-3 x n0-3 ----
#pragma unroll
    for (int m = 0; m < 4; ++m)
      af[m] = *reinterpret_cast<const bf16x8*>(&As[slot][(arow + m * 16) * 32 + kA]);
#pragma unroll
    for (int n = 0; n < 4; ++n)
      bf[n] = *reinterpret_cast<const bf16x8*>(&Bs[slot][(brow + n * 16) * 32 + kA]);
    STAGE_A(ps, pk);
    __builtin_amdgcn_s_barrier();
    __builtin_amdgcn_s_setprio(1);
#pragma unroll
    for (int m = 0; m < 4; ++m)
#pragma unroll
      for (int n = 0; n < 4; ++n)
        acc[m][n] = __builtin_amdgcn_mfma_f32_16x16x32_bf16(af[m], bf[n], acc[m][n], 0, 0, 0);
    __builtin_amdgcn_s_setprio(0);
    __builtin_amdgcn_s_barrier();
    // ---- phase 1: m4-7 x n0-3 (B frags reused in regs) ----
#pragma unroll
    for (int m = 0; m < 4; ++m)
      af[m] = *reinterpret_cast<const bf16x8*>(&As[slot][(arow + 64 + m * 16) * 32 + kA]);
    STAGE_B(ps, pk);
    asm volatile("s_waitcnt vmcnt(4)" ::: "memory");  // stage(kt+1) landed
    __builtin_amdgcn_s_barrier();                     // -> globally visible
    __builtin_amdgcn_s_setprio(1);
#pragma unroll
    for (int m = 0; m < 4; ++m)
#pragma unroll
      for (int n = 0; n < 4; ++n)
        acc[4 + m][n] = __builtin_amdgcn_mfma_f32_16x16x32_bf16(af[m], bf[n], acc[4 + m][n], 0, 0, 0);
    __builtin_amdgcn_s_setprio(0);
    __builtin_amdgcn_s_barrier();
    slot = (slot == 2) ? 0 : slot + 1;
    ps   = (ps == 2) ? 0 : ps + 1;
  }
#undef STAGE_A
#undef STAGE_B

  __syncthreads();  // full drain once, before epilogue

  // epilogue: v = acc + pd; partial += tanh(v)*Vw; reduce over 16 col-lanes
  float pd4[4], vw4[4];
#pragma unroll
  for (int nf = 0; nf < 4; ++nf) {
    int c = ns * 256 + wn * 64 + nf * 16 + l15;
    pd4[nf] = pd[b * 1024 + c];
    vw4[nf] = Vw[c];
  }
#pragma unroll
  for (int m = 0; m < 8; ++m)
#pragma unroll
    for (int r = 0; r < 4; ++r) {
      float s = 0.f;
#pragma unroll
      for (int nf = 0; nf < 4; ++nf) {
        float v = acc[m][nf][r] + pd4[nf];
        float e = __expf(2.f * v);
        s += (1.f - 2.f * __builtin_amdgcn_rcpf(e + 1.f)) * vw4[nf];
      }
      s += __shfl_xor(s, 1);
      s += __shfl_xor(s, 2);
      s += __shfl_xor(s, 4);
      s += __shfl_xor(s, 8);
      if (l15 == 0) sc2[wid][m * 16 + l4 * 4 + r] = s;
    }
  __syncthreads();
  if (tid < 256) {
    const int wmr = tid >> 7, lr = tid & 127;
    float s = sc2[wmr * 4 + 0][lr] + sc2[wmr * 4 + 1][lr] +
              sc2[wmr * 4 + 2][lr] + sc2[wmr * 4 + 3][lr];
    spart[(size_t)ns * 131072 + row0 + tid] = s;  // V_b cancels in softmax
  }
}

// ---------- R5-proven 2-phase score (small-ws fallback, f32 path) ----------
__global__ __launch_bounds__(512, 4) void score_kernel(
    const float* __restrict__ encf, const u16* __restrict__ W1s,
    const float* __restrict__ pd, const float* __restrict__ Vw,
    float* __restrict__ spart) {
  __shared__ __align__(16) u16 Bs[2][256 * 32];
  __shared__ __align__(16) u16 As[2][128 * 32];
  __shared__ float sc2[8][64];

  const int  tid  = threadIdx.x;
  const int  lane = tid & 63;
  const int  wid  = tid >> 6;
  const int  wm   = wid >> 2, wn = wid & 3;
  const int  l15  = lane & 15, l4 = lane >> 4;
  const int  bid  = blockIdx.x;
  const int  rg   = ((bid >> 5) << 3) | (bid & 7);
  const int  ns   = (bid >> 3) & 3;
  const long row0 = (long)rg * 128;
  const int  b    = rg >> 4;

  const int am = tid >> 2;
  const int ak8  = (tid & 3) * 8;
  const int aidx = am * 32 + (ak8 ^ (((am >> 1) & 3) << 3));
  const float* aptr = encf + (size_t)(row0 + am) * 1024 + ak8;
  const u16* bbase = W1s + ns * 8192;

  f32x4 acc[4][4];
#pragma unroll
  for (int mf = 0; mf < 4; ++mf)
#pragma unroll
    for (int nf = 0; nf < 4; ++nf) acc[mf][nf] = (f32x4){0, 0, 0, 0};

  const int kA = (l4 * 8) ^ (((l15 >> 1) & 3) << 3);

  {
#pragma unroll
    for (int j = 0; j < 2; ++j)
      gl2lds16(bbase + j * 4096 + tid * 8, &Bs[0][j * 4096 + tid * 8]);
    float4 a0 = *reinterpret_cast<const float4*>(aptr);
    float4 a1 = *reinterpret_cast<const float4*>(aptr + 4);
    uint4 pk;
    pk.x = pk2(a0.x, a0.y); pk.y = pk2(a0.z, a0.w);
    pk.z = pk2(a1.x, a1.y); pk.w = pk2(a1.z, a1.w);
    *reinterpret_cast<uint4*>(&As[0][aidx]) = pk;
  }
  __syncthreads();

  for (int kt = 0; kt < 32; ++kt) {
    const int cur = kt & 1, nxt = cur ^ 1;
    float4 a0, a1;
    if (kt < 31) {
      a0 = *reinterpret_cast<const float4*>(aptr + (kt + 1) * 32);
      a1 = *reinterpret_cast<const float4*>(aptr + (kt + 1) * 32 + 4);
      const u16* bsrc = bbase + (kt + 1) * 32768;
#pragma unroll
      for (int j = 0; j < 2; ++j)
        gl2lds16(bsrc + j * 4096 + tid * 8, &Bs[nxt][j * 4096 + tid * 8]);
    }
    bf16x8 af[4];
#pragma unroll
    for (int mf = 0; mf < 4; ++mf)
      af[mf] = *reinterpret_cast<const bf16x8*>(
          &As[cur][(wm * 64 + mf * 16 + l15) * 32 + kA]);
#pragma unroll
    for (int nf = 0; nf < 4; ++nf) {
      bf16x8 bfr = *reinterpret_cast<const bf16x8*>(
          &Bs[cur][(wn * 64 + nf * 16 + l15) * 32 + kA]);
#pragma unroll
      for (int mf = 0; mf < 4; ++mf)
        acc[mf][nf] = __builtin_amdgcn_mfma_f32_16x16x32_bf16(af[mf], bfr, acc[mf][nf], 0, 0, 0);
    }
    if (kt < 31) {
      uint4 pk;
      pk.x = pk2(a0.x, a0.y); pk.y = pk2(a0.z, a0.w);
      pk.z = pk2(a1.x, a1.y); pk.w = pk2(a1.z, a1.w);
      *reinterpret_cast<uint4*>(&As[nxt][aidx]) = pk;
    }
    __syncthreads();
  }

  float pd4[4], vw4[4];
#pragma unroll
  for (int nf = 0; nf < 4; ++nf) {
    int c = ns * 256 + wn * 64 + nf * 16 + l15;
    pd4[nf] = pd[b * 1024 + c];
    vw4[nf] = Vw[c];
  }
#pragma unroll
  for (int mf = 0; mf < 4; ++mf)
#pragma unroll
    for (int r = 0; r < 4; ++r) {
      float s = 0.f;
#pragma unroll
      for (int nf = 0; nf < 4; ++nf) {
        float v = acc[mf][nf][r] + pd4[nf];
        float e = __expf(2.f * v);
        s += (1.f - 2.f * __builtin_amdgcn_rcpf(e + 1.f)) * vw4[nf];
      }
      s += __shfl_xor(s, 1);
      s += __shfl_xor(s, 2);
      s += __shfl_xor(s, 4);
      s += __shfl_xor(s, 8);
      if (l15 == 0) sc2[wid][mf * 16 + l4 * 4 + r] = s;
    }
  __syncthreads();
  if (tid < 128) {
    const int wmr = tid >> 6, lr = tid & 63;
    float s = sc2[wmr * 4 + 0][lr] + sc2[wmr * 4 + 1][lr] +
              sc2[wmr * 4 + 2][lr] + sc2[wmr * 4 + 3][lr];
    spart[(size_t)ns * 131072 + row0 + tid] = s;
  }
}

// ---------- softmax over S=2048 per batch (sums the 4 N-slice partials) ----------
__global__ __launch_bounds__(512) void softmax_kernel(
    const float* __restrict__ spart, float* __restrict__ wout) {
  __shared__ float redm[8], reds[8];
  const int b = blockIdx.x, tid = threadIdx.x;
  const size_t base = (size_t)b * 2048 + tid * 4;
  float4 v = *reinterpret_cast<const float4*>(spart + base);
#pragma unroll
  for (int j = 1; j < 4; ++j) {
    float4 p = *reinterpret_cast<const float4*>(spart + (size_t)j * 131072 + base);
    v.x += p.x; v.y += p.y; v.z += p.z; v.w += p.w;
  }
  float m = fmaxf(fmaxf(v.x, v.y), fmaxf(v.z, v.w));
  for (int off = 32; off; off >>= 1) m = fmaxf(m, __shfl_xor(m, off));
  if ((tid & 63) == 0) redm[tid >> 6] = m;
  __syncthreads();
  m = fmaxf(fmaxf(fmaxf(redm[0], redm[1]), fmaxf(redm[2], redm[3])),
            fmaxf(fmaxf(redm[4], redm[5]), fmaxf(redm[6], redm[7])));
  float e0 = __expf(v.x - m), e1 = __expf(v.y - m);
  float e2 = __expf(v.z - m), e3 = __expf(v.w - m);
  float s = e0 + e1 + e2 + e3;
  for (int off = 32; off; off >>= 1) s += __shfl_xor(s, off);
  if ((tid & 63) == 0) reds[tid >> 6] = s;
  __syncthreads();
  s = reds[0] + reds[1] + reds[2] + reds[3] + reds[4] + reds[5] + reds[6] + reds[7];
  float inv = 1.0f / s;
  float4 o; o.x = e0 * inv; o.y = e1 * inv; o.z = e2 * inv; o.w = e3 * inv;
  *reinterpret_cast<float4*>(wout + (size_t)b * 2048 + tid * 4) = o;
}

// ---------- context partials (bf16 enc) ----------
__global__ __launch_bounds__(256) void context_partial_bf16(
    const float* __restrict__ w, const u16* __restrict__ encb,
    float* __restrict__ cpart) {
  const int b  = blockIdx.x;   // 64
  const int ss = blockIdx.y;   // 8
  const int e0 = threadIdx.x * 4;
  const u16* ep = encb + ((size_t)b * 2048 + (size_t)ss * 256) * 1024 + e0;
  const float* wp = w + b * 2048 + ss * 256;
  float4 acc = {0, 0, 0, 0};
#pragma unroll 4
  for (int s = 0; s < 256; ++s) {
    ushort4 v = *reinterpret_cast<const ushort4*>(ep + (size_t)s * 1024);
    float ws = wp[s];
    acc.x += ws * bf2f(v.x);
    acc.y += ws * bf2f(v.y);
    acc.z += ws * bf2f(v.z);
    acc.w += ws * bf2f(v.w);
  }
  *reinterpret_cast<float4*>(&cpart[((size_t)(b * 8 + ss)) * 1024 + e0]) = acc;
}

// ---------- context partials (f32 fallback) ----------
__global__ __launch_bounds__(256) void context_partial_f32(
    const float* __restrict__ w, const float* __restrict__ enc,
    float* __restrict__ cpart) {
  const int b  = blockIdx.x;
  const int es = blockIdx.y;
  const int ss = blockIdx.z;
  const int e  = es * 256 + threadIdx.x;
  const float* ep = enc + ((size_t)b * 2048 + (size_t)ss * 256) * 1024 + e;
  const float* wp = w + b * 2048 + ss * 256;
  float acc = 0.f;
#pragma unroll 8
  for (int s = 0; s < 256; ++s)
    acc += wp[s] * ep[(size_t)s * 1024];
  cpart[((size_t)(b * 8 + ss)) * 1024 + e] = acc;
}

__global__ __launch_bounds__(256) void context_reduce_kernel(
    const float* __restrict__ cpart, float* __restrict__ ctx) {
  const int i = blockIdx.x * 256 + threadIdx.x;
  const int b = i >> 10, e = i & 1023;
  float s = 0.f;
#pragma unroll
  for (int j = 0; j < 8; ++j) s += cpart[(size_t)(b * 8 + j) * 1024 + e];
  ctx[i] = s;
}

extern "C" void kernel_launch(void* const* d_in, const int* in_sizes, int n_in,
                              void* d_out, int out_size, void* d_ws, size_t ws_size,
                              hipStream_t stream) {
  const float* enc = (const float*)d_in[0];
  const float* dec = (const float*)d_in[1];
  const float* W1w = (const float*)d_in[2];
  const float* W1b = (const float*)d_in[3];
  const float* W2w = (const float*)d_in[4];
  const float* W2b = (const float*)d_in[5];
  const float* Vw  = (const float*)d_in[6];
  // d_in[7] = V_b: uniform shift, cancels in softmax.

  char* ws = (char*)d_ws;
  float* wout = (float*)d_out;
  float* ctx  = (float*)d_out + 64 * 2048;

  const bool big = ws_size >= ((size_t)263 << 20);
  if (big) {
    u16*   encb  = (u16*)ws;                                    // 256 MB
    u16*   W1s   = (u16*)(ws + ((size_t)256 << 20));            // 2 MB
    float* pd    = (float*)(ws + ((size_t)258 << 20));          // 256 KB
    char*  shr   = ws + ((size_t)258 << 20) + (256u << 10);
    float* pdp   = (float*)shr;                 // 4 MB, dead after reduce
    float* spart = (float*)shr;                 // 2 MB
    float* cpart = (float*)(shr + (2u << 20));  // 2 MB

    convert_kernel<<<2048, 256, 0, stream>>>(enc, encb);
    transpose_w1_kernel<<<dim3(16, 16), 256, 0, stream>>>(W1w, W1s);
    proj_dec_partial<<<dim3(16, 16), 256, 0, stream>>>(dec, W2w, pdp);
    proj_dec_reduce<<<256, 256, 0, stream>>>(pdp, W2b, W1b, pd);
    score256_kernel<<<2048, 512, 0, stream>>>(encb, W1s, pd, Vw, spart);
    softmax_kernel<<<64, 512, 0, stream>>>(spart, wout);
    context_partial_bf16<<<dim3(64, 8), 256, 0, stream>>>(wout, encb, cpart);
    context_reduce_kernel<<<256, 256, 0, stream>>>(cpart, ctx);
  } else {
    u16*   W1s   = (u16*)ws;                                   // 2 MB
    float* cpart = (float*)ws;                                 // aliases W1s (dead)
    float* pd    = (float*)(ws + (2u << 20));                  // 256 KB
    float* spart = (float*)(ws + (2u << 20) + (256u << 10));   // 2 MB

    transpose_w1_kernel<<<dim3(16, 16), 256, 0, stream>>>(W1w, W1s);
    proj_dec_kernel<<<dim3(16, 4), 256, 0, stream>>>(dec, W2w, W2b, W1b, pd);
    score_kernel<<<4096, 512, 0, stream>>>(enc, W1s, pd, Vw, spart);
    softmax_kernel<<<64, 512, 0, stream>>>(spart, wout);
    context_partial_f32<<<dim3(64, 4, 8), 256, 0, stream>>>(wout, enc, cpart);
    context_reduce_kernel<<<256, 256, 0, stream>>>(cpart, ctx);
  }
}

// Round 14
// 490.324 us; speedup vs baseline: 1.1771x; 1.1771x over previous
//
#include <hip/hip_runtime.h>

typedef unsigned short u16;
typedef unsigned int   u32;

typedef __attribute__((ext_vector_type(8))) __bf16 bf16x8;
typedef __attribute__((ext_vector_type(4))) float  f32x4;

__device__ __forceinline__ u16 f2bf(float f) {
  union { float f; u32 u; } v; v.f = f;
  return (u16)((v.u + 0x7fffu + ((v.u >> 16) & 1u)) >> 16);
}
__device__ __forceinline__ float bf2f(u16 h) {
  union { u32 u; float f; } v; v.u = ((u32)h) << 16;
  return v.f;
}
__device__ __forceinline__ u32 pk2(float a, float b) {
  return (u32)f2bf(a) | ((u32)f2bf(b) << 16);
}
__device__ __forceinline__ void gl2lds16(const void* g, void* l) {
  __builtin_amdgcn_global_load_lds(
      (const __attribute__((address_space(1))) u32*)g,
      (__attribute__((address_space(3))) u32*)l, 16, 0, 0);
}

// ---------- enc f32 -> encb bf16 (plain row-major) ----------
__global__ __launch_bounds__(256) void convert_kernel(
    const float* __restrict__ enc, u16* __restrict__ encb) {
  const size_t total = (size_t)131072 * 1024 / 8;  // 8-float groups
  const size_t stride = (size_t)gridDim.x * 256;
  for (size_t i = (size_t)blockIdx.x * 256 + threadIdx.x; i < total; i += stride) {
    float4 v0 = *reinterpret_cast<const float4*>(enc + i * 8);
    float4 v1 = *reinterpret_cast<const float4*>(enc + i * 8 + 4);
    uint4 o;
    o.x = pk2(v0.x, v0.y); o.y = pk2(v0.z, v0.w);
    o.z = pk2(v1.x, v1.y); o.w = pk2(v1.z, v1.w);
    *reinterpret_cast<uint4*>(encb + i * 8) = o;
  }
}

// ---------- W1 [K=1024][N=1024] f32 -> W1s pre-swizzled bf16 ----------
// W1s[kt][n][kk ^ ((n>>1)&3)<<3]: linear 16B-granule copy into LDS yields
// the swizzled [n][kk] layout directly.
__global__ __launch_bounds__(256) void transpose_w1_kernel(
    const float* __restrict__ W1, u16* __restrict__ W1s) {
  __shared__ float tile[64][65];
  const int k0 = blockIdx.x * 64, n0 = blockIdx.y * 64;
  const int tx = threadIdx.x & 63, ty = threadIdx.x >> 6;
#pragma unroll
  for (int i = 0; i < 16; ++i) {
    int r = ty + i * 4;
    tile[r][tx] = W1[(k0 + r) * 1024 + n0 + tx];
  }
  __syncthreads();
#pragma unroll
  for (int i = 0; i < 16; ++i) {
    int r = ty * 16 + i;
    int n = n0 + r;
    int k = k0 + tx;
    int kt = k >> 5, kk = k & 31;
    W1s[kt * 32768 + n * 32 + (kk ^ (((n >> 1) & 3) << 3))] = f2bf(tile[tx][r]);
  }
}

// ---------- pdp[ec][b][d] = sum_{e in chunk} dec[b][e] * W2[e][d] ----------
__global__ __launch_bounds__(256) void proj_dec_partial(
    const float* __restrict__ dec, const float* __restrict__ W2,
    float* __restrict__ pdp) {
  __shared__ float sdec[64][64];  // [b][e]
  const int e0 = blockIdx.x * 64, d0 = blockIdx.y * 64;
  const int dl = threadIdx.x & 63, bg = threadIdx.x >> 6;
#pragma unroll
  for (int i = 0; i < 16; ++i) {
    int flat = threadIdx.x + i * 256;  // = b*64 + e
    sdec[flat >> 6][flat & 63] = dec[(flat >> 6) * 1024 + e0 + (flat & 63)];
  }
  __syncthreads();
  const int d = d0 + dl;
  float acc[16];
#pragma unroll
  for (int i = 0; i < 16; ++i) acc[i] = 0.f;
  for (int e = 0; e < 64; ++e) {
    float w2 = W2[(size_t)(e0 + e) * 1024 + d];
#pragma unroll
    for (int bb = 0; bb < 16; ++bb)
      acc[bb] += sdec[bg * 16 + bb][e] * w2;
  }
#pragma unroll
  for (int bb = 0; bb < 16; ++bb)
    pdp[(size_t)blockIdx.x * 65536 + (size_t)(bg * 16 + bb) * 1024 + d] = acc[bb];
}

__global__ __launch_bounds__(256) void proj_dec_reduce(
    const float* __restrict__ pdp, const float* __restrict__ W2b,
    const float* __restrict__ W1b, float* __restrict__ pd) {
  const int i = blockIdx.x * 256 + threadIdx.x;  // 64*1024
  const int d = i & 1023;
  float s = W2b[d] + W1b[d];
#pragma unroll
  for (int j = 0; j < 16; ++j) s += pdp[(size_t)j * 65536 + i];
  pd[i] = s;
}

// ---------- legacy proj_dec (small-ws fallback only) ----------
__global__ __launch_bounds__(256) void proj_dec_kernel(
    const float* __restrict__ dec, const float* __restrict__ W2,
    const float* __restrict__ W2b, const float* __restrict__ W1b,
    float* __restrict__ pd) {
  __shared__ float sdec[16 * 256];
  const int dl = threadIdx.x & 63;
  const int bg = threadIdx.x >> 6;
  const int d  = blockIdx.x * 64 + dl;
  const int b0 = blockIdx.y * 16;
  float acc[4];
#pragma unroll
  for (int i = 0; i < 4; ++i) acc[i] = 0.f;
  for (int et = 0; et < 4; ++et) {
    __syncthreads();
#pragma unroll
    for (int i = 0; i < 16; ++i) {
      int flat = threadIdx.x + i * 256;
      sdec[flat] = dec[(b0 + (flat >> 8)) * 1024 + et * 256 + (flat & 255)];
    }
    __syncthreads();
    for (int e = 0; e < 256; ++e) {
      float w2 = W2[(et * 256 + e) * 1024 + d];
#pragma unroll
      for (int bb = 0; bb < 4; ++bb)
        acc[bb] += sdec[(bg * 4 + bb) * 256 + e] * w2;
    }
  }
  float bias = W2b[d] + W1b[d];
#pragma unroll
  for (int bb = 0; bb < 4; ++bb)
    pd[(b0 + bg * 4 + bb) * 1024 + d] = acc[bb] + bias;
}

// ---------- fused GEMM + tanh + V-dot, 3-slot counted-vmcnt (big-ws) ----------
// R7 geometry (proven): BM=128, BN=256, BK=32, 512 thr = 8 waves (2m x 4n),
// acc 64 VGPR (total ~120 unified regs -> 4 waves/SIMD), ~74 KB LDS ->
// 2 blocks/CU. 3-slot ring, stage slot kt+2 at step kt, vmcnt(6) before
// ds_reads, raw s_barrier after the MFMA cluster. setprio on MFMA.
// Measured R9: ~310us, MfmaUtil ~39.5%, 0 bank conflicts — the 128x256
// 2-phase structure at its L2-staging-rate ceiling (~60 B/cyc/CU).
__global__ __launch_bounds__(512, 4) void score3_kernel(
    const u16* __restrict__ encb, const u16* __restrict__ W1s,
    const float* __restrict__ pd, const float* __restrict__ Vw,
    float* __restrict__ spart) {
  __shared__ __align__(16) u16 As[3][4096];  // 3 x 8 KB  (128 r x 32 k)
  __shared__ __align__(16) u16 Bs[3][8192];  // 3 x 16 KB (256 r x 32 k)
  __shared__ float sc2[8][64];               // 2 KB

  const int  tid  = threadIdx.x;
  const int  lane = tid & 63;
  const int  wid  = tid >> 6;
  const int  wm   = wid >> 2, wn = wid & 3;
  const int  l15  = lane & 15, l4 = lane >> 4;
  const int  bid  = blockIdx.x;
  const int  rg   = ((bid >> 5) << 3) | (bid & 7);  // 4 ns of a rg share XCD
  const int  ns   = (bid >> 3) & 3;
  const long row0 = (long)rg * 128;
  const int  b    = rg >> 4;

  // A: 1 gl2lds/thread; swizzle on GLOBAL source granule, LDS dest linear.
  const int am  = tid >> 2;
  const int ajx = (tid & 3) ^ ((am >> 1) & 3);
  const u16* abf   = encb + (size_t)(row0 + am) * 1024 + ajx * 8;
  const u16* bbase = W1s + ns * 8192 + tid * 8;

#define STAGE(s, k) do { \
    gl2lds16(abf + (k) * 32, &As[s][tid * 8]); \
    gl2lds16(bbase + (size_t)(k) * 32768, &Bs[s][tid * 8]); \
    gl2lds16(bbase + (size_t)(k) * 32768 + 4096, &Bs[s][4096 + tid * 8]); \
  } while (0)

  f32x4 acc[4][4];
#pragma unroll
  for (int mf = 0; mf < 4; ++mf)
#pragma unroll
    for (int nf = 0; nf < 4; ++nf) acc[mf][nf] = (f32x4){0, 0, 0, 0};

  const int kA = (l4 * 8) ^ (((l15 >> 1) & 3) << 3);

  // prologue: stage data 0,1 into slots 0,1; wait slot 0 (3 of stage1 left)
  STAGE(0, 0);
  STAGE(1, 1);
  asm volatile("s_waitcnt vmcnt(3)" ::: "memory");
  __builtin_amdgcn_s_barrier();

#pragma unroll
  for (int kt = 0; kt < 32; ++kt) {
    const int slot = kt % 3;
    const int ps   = (kt + 2) % 3;
    const int pk   = (kt + 2) & 31;  // wraps at tail -> dummy into dead slot
    STAGE(ps, pk);                   // issue-only; lands >= 2 steps later
    asm volatile("s_waitcnt vmcnt(6)" ::: "memory");  // stage(kt) landed
    bf16x8 af[4], bf[4];
#pragma unroll
    for (int mf = 0; mf < 4; ++mf)
      af[mf] = *reinterpret_cast<const bf16x8*>(
          &As[slot][(wm * 64 + mf * 16 + l15) * 32 + kA]);
#pragma unroll
    for (int nf = 0; nf < 4; ++nf)
      bf[nf] = *reinterpret_cast<const bf16x8*>(
          &Bs[slot][(wn * 64 + nf * 16 + l15) * 32 + kA]);
    __builtin_amdgcn_s_setprio(1);
#pragma unroll
    for (int nf = 0; nf < 4; ++nf)
#pragma unroll
      for (int mf = 0; mf < 4; ++mf)
        acc[mf][nf] = __builtin_amdgcn_mfma_f32_16x16x32_bf16(af[mf], bf[nf], acc[mf][nf], 0, 0, 0);
    __builtin_amdgcn_s_setprio(0);
    __builtin_amdgcn_s_barrier();    // raw barrier: in-flight stages cross it
  }
#undef STAGE

  __syncthreads();  // full drain once, before sc2 use

  // epilogue: v = acc + pd; partial += tanh(v)*Vw; reduce over 16 col-lanes
  float pd4[4], vw4[4];
#pragma unroll
  for (int nf = 0; nf < 4; ++nf) {
    int c = ns * 256 + wn * 64 + nf * 16 + l15;
    pd4[nf] = pd[b * 1024 + c];
    vw4[nf] = Vw[c];
  }
#pragma unroll
  for (int mf = 0; mf < 4; ++mf)
#pragma unroll
    for (int r = 0; r < 4; ++r) {
      float s = 0.f;
#pragma unroll
      for (int nf = 0; nf < 4; ++nf) {
        float v = acc[mf][nf][r] + pd4[nf];
        float e = __expf(2.f * v);
        s += (1.f - 2.f * __builtin_amdgcn_rcpf(e + 1.f)) * vw4[nf];
      }
      s += __shfl_xor(s, 1);
      s += __shfl_xor(s, 2);
      s += __shfl_xor(s, 4);
      s += __shfl_xor(s, 8);
      if (l15 == 0) sc2[wid][mf * 16 + l4 * 4 + r] = s;
    }
  __syncthreads();
  if (tid < 128) {
    const int wmr = tid >> 6, lr = tid & 63;
    float s = sc2[wmr * 4 + 0][lr] + sc2[wmr * 4 + 1][lr] +
              sc2[wmr * 4 + 2][lr] + sc2[wmr * 4 + 3][lr];
    spart[(size_t)ns * 131072 + row0 + tid] = s;  // V_b cancels in softmax
  }
}

// ---------- R5-proven 2-phase score (small-ws fallback, f32 path) ----------
template <int BF>
__global__ __launch_bounds__(512, 4) void score_kernel(
    const float* __restrict__ encf, const u16* __restrict__ encb,
    const u16* __restrict__ W1s, const float* __restrict__ pd,
    const float* __restrict__ Vw, float* __restrict__ spart) {
  __shared__ __align__(16) u16 Bs[2][256 * 32];
  __shared__ __align__(16) u16 As[2][128 * 32];
  __shared__ float sc2[8][64];

  const int  tid  = threadIdx.x;
  const int  lane = tid & 63;
  const int  wid  = tid >> 6;
  const int  wm   = wid >> 2, wn = wid & 3;
  const int  l15  = lane & 15, l4 = lane >> 4;
  const int  bid  = blockIdx.x;
  const int  rg   = ((bid >> 5) << 3) | (bid & 7);
  const int  ns   = (bid >> 3) & 3;
  const long row0 = (long)rg * 128;
  const int  b    = rg >> 4;

  const int am = tid >> 2;
  const int ak8  = (tid & 3) * 8;
  const int aidx = am * 32 + (ak8 ^ (((am >> 1) & 3) << 3));
  const float* aptr = encf + (size_t)(row0 + am) * 1024 + ak8;
  const u16* bbase = W1s + ns * 8192;

  f32x4 acc[4][4];
#pragma unroll
  for (int mf = 0; mf < 4; ++mf)
#pragma unroll
    for (int nf = 0; nf < 4; ++nf) acc[mf][nf] = (f32x4){0, 0, 0, 0};

  const int kA = (l4 * 8) ^ (((l15 >> 1) & 3) << 3);

  {
#pragma unroll
    for (int j = 0; j < 2; ++j)
      gl2lds16(bbase + j * 4096 + tid * 8, &Bs[0][j * 4096 + tid * 8]);
    float4 a0 = *reinterpret_cast<const float4*>(aptr);
    float4 a1 = *reinterpret_cast<const float4*>(aptr + 4);
    uint4 pk;
    pk.x = pk2(a0.x, a0.y); pk.y = pk2(a0.z, a0.w);
    pk.z = pk2(a1.x, a1.y); pk.w = pk2(a1.z, a1.w);
    *reinterpret_cast<uint4*>(&As[0][aidx]) = pk;
  }
  __syncthreads();

  for (int kt = 0; kt < 32; ++kt) {
    const int cur = kt & 1, nxt = cur ^ 1;
    float4 a0, a1;
    if (kt < 31) {
      a0 = *reinterpret_cast<const float4*>(aptr + (kt + 1) * 32);
      a1 = *reinterpret_cast<const float4*>(aptr + (kt + 1) * 32 + 4);
      const u16* bsrc = bbase + (kt + 1) * 32768;
#pragma unroll
      for (int j = 0; j < 2; ++j)
        gl2lds16(bsrc + j * 4096 + tid * 8, &Bs[nxt][j * 4096 + tid * 8]);
    }
    bf16x8 af[4];
#pragma unroll
    for (int mf = 0; mf < 4; ++mf)
      af[mf] = *reinterpret_cast<const bf16x8*>(
          &As[cur][(wm * 64 + mf * 16 + l15) * 32 + kA]);
#pragma unroll
    for (int nf = 0; nf < 4; ++nf) {
      bf16x8 bfr = *reinterpret_cast<const bf16x8*>(
          &Bs[cur][(wn * 64 + nf * 16 + l15) * 32 + kA]);
#pragma unroll
      for (int mf = 0; mf < 4; ++mf)
        acc[mf][nf] = __builtin_amdgcn_mfma_f32_16x16x32_bf16(af[mf], bfr, acc[mf][nf], 0, 0, 0);
    }
    if (kt < 31) {
      uint4 pk;
      pk.x = pk2(a0.x, a0.y); pk.y = pk2(a0.z, a0.w);
      pk.z = pk2(a1.x, a1.y); pk.w = pk2(a1.z, a1.w);
      *reinterpret_cast<uint4*>(&As[nxt][aidx]) = pk;
    }
    __syncthreads();
  }

  float pd4[4], vw4[4];
#pragma unroll
  for (int nf = 0; nf < 4; ++nf) {
    int c = ns * 256 + wn * 64 + nf * 16 + l15;
    pd4[nf] = pd[b * 1024 + c];
    vw4[nf] = Vw[c];
  }
#pragma unroll
  for (int mf = 0; mf < 4; ++mf)
#pragma unroll
    for (int r = 0; r < 4; ++r) {
      float s = 0.f;
#pragma unroll
      for (int nf = 0; nf < 4; ++nf) {
        float v = acc[mf][nf][r] + pd4[nf];
        float e = __expf(2.f * v);
        s += (1.f - 2.f * __builtin_amdgcn_rcpf(e + 1.f)) * vw4[nf];
      }
      s += __shfl_xor(s, 1);
      s += __shfl_xor(s, 2);
      s += __shfl_xor(s, 4);
      s += __shfl_xor(s, 8);
      if (l15 == 0) sc2[wid][mf * 16 + l4 * 4 + r] = s;
    }
  __syncthreads();
  if (tid < 128) {
    const int wmr = tid >> 6, lr = tid & 63;
    float s = sc2[wmr * 4 + 0][lr] + sc2[wmr * 4 + 1][lr] +
              sc2[wmr * 4 + 2][lr] + sc2[wmr * 4 + 3][lr];
    spart[(size_t)ns * 131072 + row0 + tid] = s;
  }
}

// ---------- softmax over S=2048 per batch (sums the 4 N-slice partials) ----------
__global__ __launch_bounds__(512) void softmax_kernel(
    const float* __restrict__ spart, float* __restrict__ wout) {
  __shared__ float redm[8], reds[8];
  const int b = blockIdx.x, tid = threadIdx.x;
  const size_t base = (size_t)b * 2048 + tid * 4;
  float4 v = *reinterpret_cast<const float4*>(spart + base);
#pragma unroll
  for (int j = 1; j < 4; ++j) {
    float4 p = *reinterpret_cast<const float4*>(spart + (size_t)j * 131072 + base);
    v.x += p.x; v.y += p.y; v.z += p.z; v.w += p.w;
  }
  float m = fmaxf(fmaxf(v.x, v.y), fmaxf(v.z, v.w));
  for (int off = 32; off; off >>= 1) m = fmaxf(m, __shfl_xor(m, off));
  if ((tid & 63) == 0) redm[tid >> 6] = m;
  __syncthreads();
  m = fmaxf(fmaxf(fmaxf(redm[0], redm[1]), fmaxf(redm[2], redm[3])),
            fmaxf(fmaxf(redm[4], redm[5]), fmaxf(redm[6], redm[7])));
  float e0 = __expf(v.x - m), e1 = __expf(v.y - m);
  float e2 = __expf(v.z - m), e3 = __expf(v.w - m);
  float s = e0 + e1 + e2 + e3;
  for (int off = 32; off; off >>= 1) s += __shfl_xor(s, off);
  if ((tid & 63) == 0) reds[tid >> 6] = s;
  __syncthreads();
  s = reds[0] + reds[1] + reds[2] + reds[3] + reds[4] + reds[5] + reds[6] + reds[7];
  float inv = 1.0f / s;
  float4 o; o.x = e0 * inv; o.y = e1 * inv; o.z = e2 * inv; o.w = e3 * inv;
  *reinterpret_cast<float4*>(wout + (size_t)b * 2048 + tid * 4) = o;
}

// ---------- context partials (bf16 enc) ----------
__global__ __launch_bounds__(256) void context_partial_bf16(
    const float* __restrict__ w, const u16* __restrict__ encb,
    float* __restrict__ cpart) {
  const int b  = blockIdx.x;   // 64
  const int ss = blockIdx.y;   // 8
  const int e0 = threadIdx.x * 4;
  const u16* ep = encb + ((size_t)b * 2048 + (size_t)ss * 256) * 1024 + e0;
  const float* wp = w + b * 2048 + ss * 256;
  float4 acc = {0, 0, 0, 0};
#pragma unroll 4
  for (int s = 0; s < 256; ++s) {
    ushort4 v = *reinterpret_cast<const ushort4*>(ep + (size_t)s * 1024);
    float ws = wp[s];
    acc.x += ws * bf2f(v.x);
    acc.y += ws * bf2f(v.y);
    acc.z += ws * bf2f(v.z);
    acc.w += ws * bf2f(v.w);
  }
  *reinterpret_cast<float4*>(&cpart[((size_t)(b * 8 + ss)) * 1024 + e0]) = acc;
}

// ---------- context partials (f32 fallback) ----------
__global__ __launch_bounds__(256) void context_partial_f32(
    const float* __restrict__ w, const float* __restrict__ enc,
    float* __restrict__ cpart) {
  const int b  = blockIdx.x;
  const int es = blockIdx.y;
  const int ss = blockIdx.z;
  const int e  = es * 256 + threadIdx.x;
  const float* ep = enc + ((size_t)b * 2048 + (size_t)ss * 256) * 1024 + e;
  const float* wp = w + b * 2048 + ss * 256;
  float acc = 0.f;
#pragma unroll 8
  for (int s = 0; s < 256; ++s)
    acc += wp[s] * ep[(size_t)s * 1024];
  cpart[((size_t)(b * 8 + ss)) * 1024 + e] = acc;
}

__global__ __launch_bounds__(256) void context_reduce_kernel(
    const float* __restrict__ cpart, float* __restrict__ ctx) {
  const int i = blockIdx.x * 256 + threadIdx.x;
  const int b = i >> 10, e = i & 1023;
  float s = 0.f;
#pragma unroll
  for (int j = 0; j < 8; ++j) s += cpart[(size_t)(b * 8 + j) * 1024 + e];
  ctx[i] = s;
}

extern "C" void kernel_launch(void* const* d_in, const int* in_sizes, int n_in,
                              void* d_out, int out_size, void* d_ws, size_t ws_size,
                              hipStream_t stream) {
  const float* enc = (const float*)d_in[0];
  const float* dec = (const float*)d_in[1];
  const float* W1w = (const float*)d_in[2];
  const float* W1b = (const float*)d_in[3];
  const float* W2w = (const float*)d_in[4];
  const float* W2b = (const float*)d_in[5];
  const float* Vw  = (const float*)d_in[6];
  // d_in[7] = V_b: uniform shift, cancels in softmax.

  char* ws = (char*)d_ws;
  float* wout = (float*)d_out;
  float* ctx  = (float*)d_out + 64 * 2048;

  const bool big = ws_size >= ((size_t)263 << 20);
  if (big) {
    u16*   encb  = (u16*)ws;                                    // 256 MB
    u16*   W1s   = (u16*)(ws + ((size_t)256 << 20));            // 2 MB
    float* pd    = (float*)(ws + ((size_t)258 << 20));          // 256 KB
    char*  shr   = ws + ((size_t)258 << 20) + (256u << 10);
    float* pdp   = (float*)shr;                 // 4 MB, dead after reduce
    float* spart = (float*)shr;                 // 2 MB
    float* cpart = (float*)(shr + (2u << 20));  // 2 MB

    convert_kernel<<<2048, 256, 0, stream>>>(enc, encb);
    transpose_w1_kernel<<<dim3(16, 16), 256, 0, stream>>>(W1w, W1s);
    proj_dec_partial<<<dim3(16, 16), 256, 0, stream>>>(dec, W2w, pdp);
    proj_dec_reduce<<<256, 256, 0, stream>>>(pdp, W2b, W1b, pd);
    score3_kernel<<<4096, 512, 0, stream>>>(encb, W1s, pd, Vw, spart);
    softmax_kernel<<<64, 512, 0, stream>>>(spart, wout);
    context_partial_bf16<<<dim3(64, 8), 256, 0, stream>>>(wout, encb, cpart);
    context_reduce_kernel<<<256, 256, 0, stream>>>(cpart, ctx);
  } else {
    u16*   W1s   = (u16*)ws;                                   // 2 MB
    float* cpart = (float*)ws;                                 // aliases W1s (dead)
    float* pd    = (float*)(ws + (2u << 20));                  // 256 KB
    float* spart = (float*)(ws + (2u << 20) + (256u << 10));   // 2 MB

    transpose_w1_kernel<<<dim3(16, 16), 256, 0, stream>>>(W1w, W1s);
    proj_dec_kernel<<<dim3(16, 4), 256, 0, stream>>>(dec, W2w, W2b, W1b, pd);
    score_kernel<0><<<4096, 512, 0, stream>>>(enc, (const u16*)nullptr, W1s, pd, Vw, spart);
    softmax_kernel<<<64, 512, 0, stream>>>(spart, wout);
    context_partial_f32<<<dim3(64, 4, 8), 256, 0, stream>>>(wout, enc, cpart);
    context_reduce_kernel<<<256, 256, 0, stream>>>(cpart, ctx);
  }
}